// Round 3
// baseline (783.427 us; speedup 1.0000x reference)
//
#include <hip/hip_runtime.h>
#include <stdint.h>

// B=2,H=16,S=2048,D=64 attention. out = concat(attn [2,16,2048,2048], sv [2,16,2048,64]) fp32.
// mask int32, TRUE => masked (score -1e30 => e=0).
// Two-pass design:
//   prep: bf16 Q(scaled), K(swizzled tiles), V^T(swizzled tiles) in ws (unchanged).
//   attn pass 1: QK^T + exp -> row sums only. K reg-staged (depth-2), no LDS, no barriers.
//   attn pass 2: recompute QK^T (identical bits), store normalized attention rows in-loop
//     (streamed nt stores overlap compute), PV via et LDS round-trip with ONE raw
//     lgkm-barrier per kt (et double-buffered). K,V reg-staged -> no vmcnt-drain barriers.
// XCD-contiguous block swizzle keeps each bh's K/V L2-resident (2 MB per XCD).

#define S_DIM 2048
#define D_DIM 64
#define QT 32
#define KTILE 64
#define NKT 32
#define NT 512
#define NBH 32
#define ETS 72
#define ATTN_ELEMS ((size_t)NBH * S_DIM * S_DIM)
#define QELEMS ((size_t)NBH * S_DIM * D_DIM)   // 4194304 elems = 8 MB bf16

typedef short s16x8 __attribute__((ext_vector_type(8)));
typedef float f32x4 __attribute__((ext_vector_type(4)));

__device__ __forceinline__ unsigned short f2bf(float x) {
  unsigned int u = __float_as_uint(x);
  u += 0x7FFF + ((u >> 16) & 1);   // RNE
  return (unsigned short)(u >> 16);
}
__device__ __forceinline__ float bf2f(unsigned short h) {
  return __uint_as_float(((unsigned int)h) << 16);
}

// ---------------- pre-pass: bf16 conversion + tiling/swizzle ----------------
// K tiles: per (bh,kt): elem (r,d) at r*64 + (d ^ ((r&7)*8))   [r=s&63]
// Vt tiles: per (bh,kt): elem (d,c) at d*64 + (c ^ ((d&7)*8))  [c=s&63], value V[s][d]
extern "C" __global__ __launch_bounds__(256)
void prep_kernel(const float* __restrict__ Q, const float* __restrict__ K,
                 const float* __restrict__ V, unsigned short* __restrict__ Qb,
                 unsigned short* __restrict__ Kb, unsigned short* __restrict__ Vtb) {
  __shared__ unsigned short vtl[64 * 65];
  const int t = threadIdx.x;
  const int blk = blockIdx.x;
  if (blk < 1024) {
    const int bh = blk >> 5;
    const int kt = blk & 31;
    const float* Ksrc = K + ((size_t)bh * S_DIM + kt * KTILE) * D_DIM;
    const float* Vsrc = V + ((size_t)bh * S_DIM + kt * KTILE) * D_DIM;
    unsigned short* Kdst = Kb + ((size_t)bh * S_DIM + kt * KTILE) * D_DIM;
    unsigned short* Vdst = Vtb + ((size_t)bh * S_DIM + kt * KTILE) * D_DIM;
#pragma unroll
    for (int i = 0; i < 2; ++i) {
      const int f = t + i * 256;
      const int row = f >> 3, db = f & 7;
      const float* s = Ksrc + row * 64 + db * 8;
      s16x8 v;
#pragma unroll
      for (int j = 0; j < 8; ++j) v[j] = (short)f2bf(s[j]);
      *(s16x8*)(Kdst + row * 64 + ((db * 8) ^ ((row & 7) * 8))) = v;
    }
#pragma unroll
    for (int i = 0; i < 4; ++i) {
      const int f = t + i * 256;
      const int row = f >> 4, c4 = f & 15;
      const float4 vv = *(const float4*)(Vsrc + row * 64 + c4 * 4);
      vtl[(c4 * 4 + 0) * 65 + row] = f2bf(vv.x);
      vtl[(c4 * 4 + 1) * 65 + row] = f2bf(vv.y);
      vtl[(c4 * 4 + 2) * 65 + row] = f2bf(vv.z);
      vtl[(c4 * 4 + 3) * 65 + row] = f2bf(vv.w);
    }
    __syncthreads();
#pragma unroll
    for (int i = 0; i < 2; ++i) {
      const int f = t + i * 256;
      const int d = f >> 3, b8 = f & 7;
      s16x8 v;
#pragma unroll
      for (int j = 0; j < 8; ++j) v[j] = (short)vtl[d * 65 + b8 * 8 + j];
      *(s16x8*)(Vdst + d * 64 + ((b8 * 8) ^ ((d & 7) * 8))) = v;
    }
  } else {
    const size_t base = (size_t)(blk - 1024) * 2048 + (size_t)t * 8;
    const float4 a = *(const float4*)(Q + base);
    const float4 b2 = *(const float4*)(Q + base + 4);
    s16x8 v;
    v[0] = (short)f2bf(a.x * 0.125f);  v[1] = (short)f2bf(a.y * 0.125f);
    v[2] = (short)f2bf(a.z * 0.125f);  v[3] = (short)f2bf(a.w * 0.125f);
    v[4] = (short)f2bf(b2.x * 0.125f); v[5] = (short)f2bf(b2.y * 0.125f);
    v[6] = (short)f2bf(b2.z * 0.125f); v[7] = (short)f2bf(b2.w * 0.125f);
    *(s16x8*)(Qb + base) = v;
  }
}

// ---------------- main kernel ----------------
extern "C" __global__ __launch_bounds__(NT, 4)
void attn_kernel(const int* __restrict__ Mask, const unsigned short* __restrict__ Qb,
                 const unsigned short* __restrict__ Kb, const unsigned short* __restrict__ Vtb,
                 float* __restrict__ Out) {
  __shared__ unsigned short et[2][QT * ETS];   // 9 KB (double-buffered)
  __shared__ float sums_part[8 * 16];
  __shared__ float inv_sums[QT];

  const int t = threadIdx.x;
  const int lane = t & 63;
  const int wave = t >> 6;     // 0..7
  const int l15 = lane & 15;
  const int quad = lane >> 4;  // 0..3
  const int tq = wave >> 2;    // 0..1
  const int tn = wave & 3;     // 0..3

  // XCD-contiguous swizzle: 2048 blocks = 8 XCDs * 256. Each XCD owns 4 consecutive bh
  // -> its 4 MB L2 holds those K/V tiles (2 MB) across BOTH passes.
  const int blk0 = blockIdx.x;
  const int blk = (blk0 & 7) * 256 + (blk0 >> 3);
  const int qt_idx = blk & 63;
  const int bh = blk >> 6;
  const int q0 = qt_idx * QT;

  const unsigned short* kbg = Kb + (size_t)bh * S_DIM * D_DIM;
  const unsigned short* vbg = Vtb + (size_t)bh * S_DIM * D_DIM;

  // Q A-fragments (row = q0+tq*16+l15, k = c*32+quad*8+j), pre-scaled bf16
  const unsigned short* qrow = Qb + ((size_t)bh * S_DIM + q0 + tq * 16 + l15) * D_DIM;
  const s16x8 qf0 = *(const s16x8*)(qrow + quad * 8);
  const s16x8 qf1 = *(const s16x8*)(qrow + 32 + quad * 8);

  // B-fragment addressing (same math as the old LDS path; tiles are stored swizzled,
  // so reading global with the same XOR yields exactly the MFMA lane mapping; each
  // wave-instruction covers whole 64B sectors -> dense L2 transactions).
  const int krow = tn * 16 + l15;       // QK: local k row / PV: local d row
  const int sw = (l15 & 7) * 8;
  const int o0 = (quad * 8) ^ sw;
  const int o1 = (32 + quad * 8) ^ sw;
  const unsigned short* kR = kbg + krow * 64;   // + kt*4096 per tile
  const unsigned short* vR = vbg + krow * 64;

  // mask bits for this thread's column, hoisted out of both loops
  const int* mrow = Mask + (bh >> 4) * S_DIM + tn * 16 + l15;
  unsigned pm = 0;
#pragma unroll
  for (int kt = 0; kt < NKT; ++kt) pm |= (mrow[kt * KTILE] ? 1u : 0u) << kt;

  const int erow0 = tq * 16 + quad * 4;

  // ---------------- pass 1: row sums (no LDS, no barriers) ----------------
  float rs[4] = {0.f, 0.f, 0.f, 0.f};
  {
    s16x8 kf0[3], kf1[3];
    kf0[0] = *(const s16x8*)(kR + o0);
    kf1[0] = *(const s16x8*)(kR + o1);
    kf0[1] = *(const s16x8*)(kR + 4096 + o0);
    kf1[1] = *(const s16x8*)(kR + 4096 + o1);
#pragma unroll
    for (int kt = 0; kt < NKT; ++kt) {
      const int cur = kt % 3;
      if (kt + 2 < NKT) {
        const int nx = (kt + 2) % 3;
        kf0[nx] = *(const s16x8*)(kR + (kt + 2) * 4096 + o0);
        kf1[nx] = *(const s16x8*)(kR + (kt + 2) * 4096 + o1);
      }
      f32x4 sc = {0.f, 0.f, 0.f, 0.f};
      sc = __builtin_amdgcn_mfma_f32_16x16x32_bf16(qf0, kf0[cur], sc, 0, 0, 0);
      sc = __builtin_amdgcn_mfma_f32_16x16x32_bf16(qf1, kf1[cur], sc, 0, 0, 0);
      const int m = (pm >> kt) & 1;
#pragma unroll
      for (int r = 0; r < 4; ++r) {
        const float ev = m ? 0.f : __expf(sc[r]);
        rs[r] += bf2f(f2bf(ev));       // bf16-rounded, identical to pass-2 values
      }
    }
  }

  // row-sum reduction: 16 lanes sharing quad hold same rows
#pragma unroll
  for (int o = 1; o < 16; o <<= 1) {
#pragma unroll
    for (int r = 0; r < 4; ++r) rs[r] += __shfl_xor(rs[r], o);
  }
  if (l15 == 0) {
#pragma unroll
    for (int r = 0; r < 4; ++r) sums_part[wave * 16 + quad * 4 + r] = rs[r];
  }
  __syncthreads();
  if (t < QT) {
    const int tqi = t >> 4, rl = t & 15;
    float s = 0.f;
#pragma unroll
    for (int w = 0; w < 4; ++w) s += sums_part[(tqi * 4 + w) * 16 + rl];
    inv_sums[t] = 1.f / fmaxf(s, 1e-30f);
  }
  __syncthreads();

  float inv_r[4];
#pragma unroll
  for (int r = 0; r < 4; ++r) inv_r[r] = inv_sums[erow0 + r];

  // ---------------- pass 2: recompute + streamed stores + PV ----------------
  f32x4 pv = {0.f, 0.f, 0.f, 0.f};
  float* ao = Out + (size_t)bh * S_DIM * S_DIM + (size_t)q0 * S_DIM + tn * 16 + l15;
  {
    s16x8 kf0[3], kf1[3], vf0[3], vf1[3];
    kf0[0] = *(const s16x8*)(kR + o0);
    kf1[0] = *(const s16x8*)(kR + o1);
    vf0[0] = *(const s16x8*)(vR + o0);
    vf1[0] = *(const s16x8*)(vR + o1);
    kf0[1] = *(const s16x8*)(kR + 4096 + o0);
    kf1[1] = *(const s16x8*)(kR + 4096 + o1);
    vf0[1] = *(const s16x8*)(vR + 4096 + o0);
    vf1[1] = *(const s16x8*)(vR + 4096 + o1);
#pragma unroll
    for (int kt = 0; kt < NKT; ++kt) {
      const int cur = kt % 3;
      if (kt + 2 < NKT) {
        const int nx = (kt + 2) % 3;
        kf0[nx] = *(const s16x8*)(kR + (kt + 2) * 4096 + o0);
        kf1[nx] = *(const s16x8*)(kR + (kt + 2) * 4096 + o1);
        vf0[nx] = *(const s16x8*)(vR + (kt + 2) * 4096 + o0);
        vf1[nx] = *(const s16x8*)(vR + (kt + 2) * 4096 + o1);
      }
      f32x4 sc = {0.f, 0.f, 0.f, 0.f};
      sc = __builtin_amdgcn_mfma_f32_16x16x32_bf16(qf0, kf0[cur], sc, 0, 0, 0);
      sc = __builtin_amdgcn_mfma_f32_16x16x32_bf16(qf1, kf1[cur], sc, 0, 0, 0);
      const int m = (pm >> kt) & 1;
      unsigned short* etp = et[kt & 1];
      unsigned short e[4];
#pragma unroll
      for (int r = 0; r < 4; ++r) {
        const float ev = m ? 0.f : __expf(sc[r]);
        e[r] = f2bf(ev);
        etp[(erow0 + r) * ETS + tn * 16 + l15] = e[r];
      }
      // streamed, normalized attention stores (overlap compute; no end burst)
      float* col = ao + kt * KTILE;
      __builtin_nontemporal_store(bf2f(e[0]) * inv_r[0], col + (size_t)(erow0 + 0) * S_DIM);
      __builtin_nontemporal_store(bf2f(e[1]) * inv_r[1], col + (size_t)(erow0 + 1) * S_DIM);
      __builtin_nontemporal_store(bf2f(e[2]) * inv_r[2], col + (size_t)(erow0 + 2) * S_DIM);
      __builtin_nontemporal_store(bf2f(e[3]) * inv_r[3], col + (size_t)(erow0 + 3) * S_DIM);
      // et-visibility barrier WITHOUT vmcnt drain: own ds_writes flushed via lgkmcnt(0),
      // cross-wave visibility via s_barrier. K/V prefetch loads + nt stores stay in flight.
      __builtin_amdgcn_sched_barrier(0);
      asm volatile("s_waitcnt lgkmcnt(0)" ::: "memory");
      __builtin_amdgcn_s_barrier();
      __builtin_amdgcn_sched_barrier(0);
      {
        const s16x8 a0 = *(const s16x8*)(etp + (tq * 16 + l15) * ETS + quad * 8);
        pv = __builtin_amdgcn_mfma_f32_16x16x32_bf16(a0, vf0[cur], pv, 0, 0, 0);
        const s16x8 a1 = *(const s16x8*)(etp + (tq * 16 + l15) * ETS + 32 + quad * 8);
        pv = __builtin_amdgcn_mfma_f32_16x16x32_bf16(a1, vf1[cur], pv, 0, 0, 0);
      }
    }
  }

  // sum_value (nontemporal: pure streaming output)
  {
    float* svo = Out + ATTN_ELEMS + ((size_t)bh * S_DIM + q0) * D_DIM;
#pragma unroll
    for (int r = 0; r < 4; ++r)
      __builtin_nontemporal_store(pv[r] * inv_r[r],
                                  svo + (size_t)(erow0 + r) * D_DIM + tn * 16 + l15);
  }
}

extern "C" void kernel_launch(void* const* d_in, const int* in_sizes, int n_in,
                              void* d_out, int out_size, void* d_ws, size_t ws_size,
                              hipStream_t stream) {
  const float* Q = (const float*)d_in[0];
  const float* K = (const float*)d_in[1];
  const float* V = (const float*)d_in[2];
  const int* M = (const int*)d_in[3];
  float* out = (float*)d_out;
  unsigned short* Qb = (unsigned short*)d_ws;          // needs 24 MB of ws
  unsigned short* Kb = Qb + QELEMS;
  unsigned short* Vtb = Kb + QELEMS;
  hipLaunchKernelGGL(prep_kernel, dim3(3072), dim3(256), 0, stream, Q, K, V, Qb, Kb, Vtb);
  hipLaunchKernelGGL(attn_kernel, dim3(2048), dim3(NT), 0, stream, M, Qb, Kb, Vtb, out);
}

// Round 4
// 733.148 us; speedup vs baseline: 1.0686x; 1.0686x over previous
//
#include <hip/hip_runtime.h>
#include <stdint.h>

// B=2,H=16,S=2048,D=64 attention. out = concat(attn [2,16,2048,2048], sv [2,16,2048,64]) fp32.
// mask int32, TRUE => masked (score -1e30 => e=0).
// Strategy (r2 structure + occupancy): prep writes bf16 Q(scaled), K(swizzled tiles),
// V^T(swizzled tiles) to ws; main kernel stages K/V via global_load_lds (full-iteration
// prefetch distance across a raw et-barrier that does NOT drain vmcnt), MFMA QK^T + PV,
// e kept in 64 VGPRs, nt end-burst attention stores. QT=16/NT=256 -> ~37 KB LDS/block,
// 4 blocks/CU resident (vs 2): barrier stalls of one block hide under others' work.
// Mask hoisted to a 32-bit bitmask. XCD-contiguous swizzle (4096 = 8*512, bijective).

#define S_DIM 2048
#define D_DIM 64
#define QT 16
#define KTILE 64
#define NKT 32
#define NT 256
#define NBH 32
#define ETS 72
#define ATTN_ELEMS ((size_t)NBH * S_DIM * S_DIM)
#define QELEMS ((size_t)NBH * S_DIM * D_DIM)   // 4194304 elems = 8 MB bf16

typedef short s16x8 __attribute__((ext_vector_type(8)));
typedef float f32x4 __attribute__((ext_vector_type(4)));

__device__ __forceinline__ unsigned short f2bf(float x) {
  unsigned int u = __float_as_uint(x);
  u += 0x7FFF + ((u >> 16) & 1);   // RNE
  return (unsigned short)(u >> 16);
}
__device__ __forceinline__ float bf2f(unsigned short h) {
  return __uint_as_float(((unsigned int)h) << 16);
}

__device__ __forceinline__ void glds16(const void* g, void* l) {
  __builtin_amdgcn_global_load_lds(
      (const __attribute__((address_space(1))) unsigned int*)g,
      (__attribute__((address_space(3))) unsigned int*)l, 16, 0, 0);
}

// ---------------- pre-pass: bf16 conversion + tiling/swizzle ----------------
// K tiles: per (bh,kt): elem (r,d) at r*64 + (d ^ ((r&7)*8))   [r=s&63]
// Vt tiles: per (bh,kt): elem (d,c) at d*64 + (c ^ ((d&7)*8))  [c=s&63], value V[s][d]
extern "C" __global__ __launch_bounds__(256)
void prep_kernel(const float* __restrict__ Q, const float* __restrict__ K,
                 const float* __restrict__ V, unsigned short* __restrict__ Qb,
                 unsigned short* __restrict__ Kb, unsigned short* __restrict__ Vtb) {
  __shared__ unsigned short vtl[64 * 65];
  const int t = threadIdx.x;
  const int blk = blockIdx.x;
  if (blk < 1024) {
    const int bh = blk >> 5;
    const int kt = blk & 31;
    const float* Ksrc = K + ((size_t)bh * S_DIM + kt * KTILE) * D_DIM;
    const float* Vsrc = V + ((size_t)bh * S_DIM + kt * KTILE) * D_DIM;
    unsigned short* Kdst = Kb + ((size_t)bh * S_DIM + kt * KTILE) * D_DIM;
    unsigned short* Vdst = Vtb + ((size_t)bh * S_DIM + kt * KTILE) * D_DIM;
#pragma unroll
    for (int i = 0; i < 2; ++i) {
      const int f = t + i * 256;
      const int row = f >> 3, db = f & 7;
      const float* s = Ksrc + row * 64 + db * 8;
      s16x8 v;
#pragma unroll
      for (int j = 0; j < 8; ++j) v[j] = (short)f2bf(s[j]);
      *(s16x8*)(Kdst + row * 64 + ((db * 8) ^ ((row & 7) * 8))) = v;
    }
#pragma unroll
    for (int i = 0; i < 4; ++i) {
      const int f = t + i * 256;
      const int row = f >> 4, c4 = f & 15;
      const float4 vv = *(const float4*)(Vsrc + row * 64 + c4 * 4);
      vtl[(c4 * 4 + 0) * 65 + row] = f2bf(vv.x);
      vtl[(c4 * 4 + 1) * 65 + row] = f2bf(vv.y);
      vtl[(c4 * 4 + 2) * 65 + row] = f2bf(vv.z);
      vtl[(c4 * 4 + 3) * 65 + row] = f2bf(vv.w);
    }
    __syncthreads();
#pragma unroll
    for (int i = 0; i < 2; ++i) {
      const int f = t + i * 256;
      const int d = f >> 3, b8 = f & 7;
      s16x8 v;
#pragma unroll
      for (int j = 0; j < 8; ++j) v[j] = (short)vtl[d * 65 + b8 * 8 + j];
      *(s16x8*)(Vdst + d * 64 + ((b8 * 8) ^ ((d & 7) * 8))) = v;
    }
  } else {
    const size_t base = (size_t)(blk - 1024) * 2048 + (size_t)t * 8;
    const float4 a = *(const float4*)(Q + base);
    const float4 b2 = *(const float4*)(Q + base + 4);
    s16x8 v;
    v[0] = (short)f2bf(a.x * 0.125f);  v[1] = (short)f2bf(a.y * 0.125f);
    v[2] = (short)f2bf(a.z * 0.125f);  v[3] = (short)f2bf(a.w * 0.125f);
    v[4] = (short)f2bf(b2.x * 0.125f); v[5] = (short)f2bf(b2.y * 0.125f);
    v[6] = (short)f2bf(b2.z * 0.125f); v[7] = (short)f2bf(b2.w * 0.125f);
    *(s16x8*)(Qb + base) = v;
  }
}

// ---------------- main kernel ----------------
// 4 waves/block, block covers 16 q-rows x all 2048 k. wave tn owns k/d cols tn*16..+15.
extern "C" __global__ __launch_bounds__(NT, 4)
void attn_kernel(const int* __restrict__ Mask, const unsigned short* __restrict__ Qb,
                 const unsigned short* __restrict__ Kb, const unsigned short* __restrict__ Vtb,
                 float* __restrict__ Out) {
  __shared__ unsigned short bufK[2][KTILE * D_DIM];   // 16 KB
  __shared__ unsigned short bufV[2][KTILE * D_DIM];   // 16 KB
  __shared__ unsigned short et[QT * ETS];             // 2.25 KB
  __shared__ float sums_part[4 * 16];
  __shared__ float inv_sums[QT];

  const int t = threadIdx.x;
  const int lane = t & 63;
  const int wave = t >> 6;     // 0..3 = tn
  const int l15 = lane & 15;
  const int quad = lane >> 4;  // 0..3
  const int tn = wave;

  // XCD-contiguous swizzle: 4096 blocks = 8 XCDs * 512. Each XCD owns 4 consecutive bh
  // -> its 4 MB L2 holds those K/V tiles (2 MB).
  const int blk0 = blockIdx.x;
  const int blk = (blk0 & 7) * 512 + (blk0 >> 3);
  const int qt_idx = blk & 127;
  const int bh = blk >> 7;
  const int q0 = qt_idx * QT;

  const char* kbase = (const char*)(Kb + (size_t)bh * S_DIM * D_DIM);
  const char* vbase = (const char*)(Vtb + (size_t)bh * S_DIM * D_DIM);

  // mask bits for this thread's k-column, hoisted out of the loop
  const int* mrow = Mask + (bh >> 4) * S_DIM + tn * 16 + l15;
  unsigned pm = 0;
#pragma unroll
  for (int kt = 0; kt < NKT; ++kt) pm |= (mrow[kt * KTILE] ? 1u : 0u) << kt;

  // Q A-fragments (row = q0+l15, k = c*32+quad*8+j), pre-scaled bf16
  const unsigned short* qrow = Qb + ((size_t)bh * S_DIM + q0 + l15) * D_DIM;
  const s16x8 qf0 = *(const s16x8*)(qrow + quad * 8);
  const s16x8 qf1 = *(const s16x8*)(qrow + 32 + quad * 8);

  // prologue: stage tile 0 (4 waves x 1 KB per glds; 2 glds per 8 KB tile)
  glds16(kbase + t * 16, (char*)bufK[0] + wave * 1024);
  glds16(kbase + 4096 + t * 16, (char*)bufK[0] + 4096 + wave * 1024);
  glds16(vbase + t * 16, (char*)bufV[0] + wave * 1024);
  glds16(vbase + 4096 + t * 16, (char*)bufV[0] + 4096 + wave * 1024);

  f32x4 pv = {0.f, 0.f, 0.f, 0.f};
  float rs[4] = {0.f, 0.f, 0.f, 0.f};
  unsigned int ereg[NKT][2];

  const int krow = tn * 16 + l15;     // QK: local k row / PV: local d row (0..63)
  const int sw = (l15 & 7) * 8;       // XOR swizzle for bufK/bufV reads
  const int erow0 = quad * 4;

#pragma unroll
  for (int kt = 0; kt < NKT; ++kt) {
    const int p = kt & 1;
    __syncthreads();                  // drains glds(kt) [vmcnt(0)]; PV(kt-1) done with buf[1-p];
                                      // also separates et read(kt-1) from et write(kt)
    if (kt + 1 < NKT) {               // issue next-tile prefetch NOW: stays in flight across the
                                      // raw et-barrier below -> cover = full iteration
      const size_t off = (size_t)(kt + 1) * 8192;
      glds16(kbase + off + t * 16, (char*)bufK[1 - p] + wave * 1024);
      glds16(kbase + off + 4096 + t * 16, (char*)bufK[1 - p] + 4096 + wave * 1024);
      glds16(vbase + off + t * 16, (char*)bufV[1 - p] + wave * 1024);
      glds16(vbase + off + 4096 + t * 16, (char*)bufV[1 - p] + 4096 + wave * 1024);
    }
    const int m = (pm >> kt) & 1;
    const unsigned short* kb = bufK[p];
    f32x4 sc = {0.f, 0.f, 0.f, 0.f};
    {
      const s16x8 b0 = *(const s16x8*)(kb + krow * 64 + ((quad * 8) ^ sw));
      sc = __builtin_amdgcn_mfma_f32_16x16x32_bf16(qf0, b0, sc, 0, 0, 0);
      const s16x8 b1 = *(const s16x8*)(kb + krow * 64 + ((32 + quad * 8) ^ sw));
      sc = __builtin_amdgcn_mfma_f32_16x16x32_bf16(qf1, b1, sc, 0, 0, 0);
    }
    unsigned short e[4];
#pragma unroll
    for (int r = 0; r < 4; ++r) {
      const float ev = m ? 0.f : __expf(sc[r]);
      e[r] = f2bf(ev);
      rs[r] += bf2f(e[r]);
      et[(erow0 + r) * ETS + tn * 16 + l15] = e[r];
    }
    ereg[kt][0] = (unsigned int)e[0] | ((unsigned int)e[1] << 16);
    ereg[kt][1] = (unsigned int)e[2] | ((unsigned int)e[3] << 16);
    // et-visibility barrier WITHOUT vmcnt drain (keeps glds(kt+1) in flight):
    // own et ds_writes flushed via lgkmcnt(0); cross-wave visibility via s_barrier.
    // glds(kt+1) targets buf[1-p], first read only after next __syncthreads (vmcnt drain).
    __builtin_amdgcn_sched_barrier(0);
    asm volatile("s_waitcnt lgkmcnt(0)" ::: "memory");
    __builtin_amdgcn_s_barrier();
    __builtin_amdgcn_sched_barrier(0);
    const unsigned short* vb = bufV[p];
    {
      const s16x8 a0 = *(const s16x8*)(et + l15 * ETS + quad * 8);
      const s16x8 b0 = *(const s16x8*)(vb + krow * 64 + ((quad * 8) ^ sw));
      pv = __builtin_amdgcn_mfma_f32_16x16x32_bf16(a0, b0, pv, 0, 0, 0);
      const s16x8 a1 = *(const s16x8*)(et + l15 * ETS + 32 + quad * 8);
      const s16x8 b1 = *(const s16x8*)(vb + krow * 64 + ((32 + quad * 8) ^ sw));
      pv = __builtin_amdgcn_mfma_f32_16x16x32_bf16(a1, b1, pv, 0, 0, 0);
    }
  }

  // row-sum reduction: 16 lanes sharing quad hold same rows
#pragma unroll
  for (int o = 1; o < 16; o <<= 1) {
#pragma unroll
    for (int r = 0; r < 4; ++r) rs[r] += __shfl_xor(rs[r], o);
  }
  if (l15 == 0) {
#pragma unroll
    for (int r = 0; r < 4; ++r) sums_part[wave * 16 + quad * 4 + r] = rs[r];
  }
  __syncthreads();
  if (t < QT) {
    float s = 0.f;
#pragma unroll
    for (int w = 0; w < 4; ++w) s += sums_part[w * 16 + t];
    inv_sums[t] = 1.f / fmaxf(s, 1e-30f);
  }
  __syncthreads();

  float inv_r[4];
#pragma unroll
  for (int r = 0; r < 4; ++r) inv_r[r] = inv_sums[erow0 + r];

  // sum_value (nontemporal: pure streaming output)
  {
    float* svo = Out + ATTN_ELEMS + ((size_t)bh * S_DIM + q0) * D_DIM;
#pragma unroll
    for (int r = 0; r < 4; ++r)
      __builtin_nontemporal_store(pv[r] * inv_r[r],
                                  svo + (size_t)(erow0 + r) * D_DIM + tn * 16 + l15);
  }

  // attention: direct nontemporal b32 stores from registers.
  // Per wave-instr: 4 rows x 64 B contiguous segments — fully coalesced.
  float* ao = Out + (size_t)bh * S_DIM * S_DIM + (size_t)q0 * S_DIM + tn * 16 + l15;
#pragma unroll
  for (int kt = 0; kt < NKT; ++kt) {
    float* col = ao + kt * KTILE;
    __builtin_nontemporal_store(bf2f((unsigned short)(ereg[kt][0] & 0xFFFFu)) * inv_r[0],
                                col + (size_t)(erow0 + 0) * S_DIM);
    __builtin_nontemporal_store(bf2f((unsigned short)(ereg[kt][0] >> 16)) * inv_r[1],
                                col + (size_t)(erow0 + 1) * S_DIM);
    __builtin_nontemporal_store(bf2f((unsigned short)(ereg[kt][1] & 0xFFFFu)) * inv_r[2],
                                col + (size_t)(erow0 + 2) * S_DIM);
    __builtin_nontemporal_store(bf2f((unsigned short)(ereg[kt][1] >> 16)) * inv_r[3],
                                col + (size_t)(erow0 + 3) * S_DIM);
  }
}

extern "C" void kernel_launch(void* const* d_in, const int* in_sizes, int n_in,
                              void* d_out, int out_size, void* d_ws, size_t ws_size,
                              hipStream_t stream) {
  const float* Q = (const float*)d_in[0];
  const float* K = (const float*)d_in[1];
  const float* V = (const float*)d_in[2];
  const int* M = (const int*)d_in[3];
  float* out = (float*)d_out;
  unsigned short* Qb = (unsigned short*)d_ws;          // needs 24 MB of ws
  unsigned short* Kb = Qb + QELEMS;
  unsigned short* Vtb = Kb + QELEMS;
  hipLaunchKernelGGL(prep_kernel, dim3(3072), dim3(256), 0, stream, Q, K, V, Qb, Kb, Vtb);
  hipLaunchKernelGGL(attn_kernel, dim3(4096), dim3(NT), 0, stream, M, Qb, Kb, Vtb, out);
}